// Round 5
// baseline (216.494 us; speedup 1.0000x reference)
//
#include <hip/hip_runtime.h>
#include <hip/hip_bf16.h>

typedef __bf16 bf16x8_t __attribute__((ext_vector_type(8)));
typedef float floatx4_t __attribute__((ext_vector_type(4)));

#define H 128
#define BATCH 256
#define SEQ 1024
#define NROWS_TOTAL (BATCH * SEQ)            // 262144 rows of x
#define STEP_ELEMS 33521664.0f               // 256*1023*128
#define GRID 512
#define NT (4096 / GRID)                     // 8 tiles per block

// ws layout: [0, 32768)      : Dpack, bf16, MFMA-B-fragment order [kt][n][lane][j]
//            [32768, 32776)  : accum[0]=step_sum, accum[1]=l2_sum
//            [65536, 131072) : T = A*A, fp32 row-major
//
// Algebra: f(y)=y@C.T is linear, so RK4 collapses to y1 = y·(I + D),
// D = A + A^2/2 + A^3/6 + A^4/24, A = C^T (truncated expm). Main pass is one
// streaming GEMM P = y·D (bf16 MFMA on the small correction; residual (y-x1)
// kept in exact fp32), reading x exactly once: 134 MB -> HBM floor ~20 us.
// v5 (resubmit — R4 failure was container-level, kernel audited clean):
// double-buffered Atile, ONE barrier/tile, next-tile loads issued into regs
// before MFMA (T14 issue-early/write-late), epilogue fp32 loads issued BEFORE
// the prefetch so (in-order vmcnt) their consumption doesn't wait on next
// tile's HBM traffic.

// ---- prep stage 1: T = A*A (A = C^T), plus l2 term and accumulator init ----
__global__ __launch_bounds__(256) void prep_p1(const float* __restrict__ C,
                                               float* __restrict__ T,
                                               float* __restrict__ accum) {
  int e = blockIdx.x * 256 + threadIdx.x;    // 64 WGs * 256 = 16384 elements
  int i = e >> 7, j = e & 127;
  const float* Ci = C + i;                   // C[k][i], stride H — wave-broadcast
  const float* Cj = C + j * H;               // own row, stride 1
  float s = 0.f;
  #pragma unroll 8
  for (int k = 0; k < H; k++) s += Ci[k * H] * Cj[k];
  T[e] = s;

  if (blockIdx.x == 0) {
    float l2 = 0.f;
    for (int q = threadIdx.x; q < H * H; q += 256) {
      float c = C[q], c2 = c * c;
      l2 += c2 * c2;                         // sum C^4
    }
    #pragma unroll
    for (int off = 32; off > 0; off >>= 1) l2 += __shfl_down(l2, off);
    __shared__ float red[4];
    if ((threadIdx.x & 63) == 0) red[threadIdx.x >> 6] = l2;
    __syncthreads();
    if (threadIdx.x == 0) {
      accum[0] = 0.f;
      accum[1] = red[0] + red[1] + red[2] + red[3];
    }
  }
}

// ---- prep stage 2: D = A + T/2 + (T*A)/6 + (T*T)/24, packed to MFMA B-frag layout ----
__global__ __launch_bounds__(256) void prep_p2(const float* __restrict__ C,
                                               const float* __restrict__ T,
                                               __bf16* __restrict__ Dpack) {
  int e = blockIdx.x * 256 + threadIdx.x;
  int i = e >> 7, j = e & 127;
  const float* Ti = T + i * H;               // wave-broadcast row
  const float* Cj = C + j * H;               // own row
  const float* Tj = T + j;                   // column — L2-resident
  float s3 = 0.f, s4 = 0.f;
  #pragma unroll 8
  for (int k = 0; k < H; k++) {
    float t = Ti[k];
    s3 += t * Cj[k];
    s4 += t * Tj[k * H];
  }
  float d = C[j * H + i] + 0.5f * Ti[j] + s3 * (1.f / 6.f) + s4 * (1.f / 24.f);
  // pack: frag(kt,n), lane lanep, elem je holds D[kt*32 + (lanep>>4)*8 + je][n*16 + (lanep&15)]
  int kt = i >> 5, lq = (i >> 3) & 3, je = i & 7;
  int n = j >> 4, mm = j & 15;
  int lanep = lq * 16 + mm;
  Dpack[(size_t)(((kt * 8 + n) * 64 + lanep) * 8 + je)] = (__bf16)d;
}

// ---- main streaming pass: P = y*D via MFMA, residual + square + reduce ----
// 512 threads = 8 waves; wave w owns output columns [16w, 16w+16).
__global__ __launch_bounds__(512, 4) void sindy_main(const float* __restrict__ x,
                                                     const __bf16* __restrict__ Dpack,
                                                     float* __restrict__ accum) {
  // double-buffered x-tile as bf16 MFMA-A fragments: [buf][rowg][kt][lane][j],
  // 2 x 16 KB, linear per-lane frag addressing -> conflict-free b128 LDS traffic
  __shared__ __align__(16) __bf16 Atile[2][4][4][64][8];

  int tid = threadIdx.x;
  int lane = tid & 63;
  int wave = tid >> 6;                       // 0..7 = B n-frag index
  int m = lane & 15, quad = lane >> 4;
  int col = (wave << 4) + m;                 // output column of this lane

  // B fragments for this wave's 16-col strip: 4 frags = 16 VGPRs
  bf16x8_t breg[4];
  const bf16x8_t* Dp = (const bf16x8_t*)Dpack;
  #pragma unroll
  for (int kt = 0; kt < 4; kt++) breg[kt] = Dp[(kt * 8 + wave) * 64 + lane];

  // staging coords: thread loads row (tid>>3), 16-col group (tid&7)
  int srow_st = tid >> 3;                    // 0..63
  int g2 = tid & 7;
  int rowg_st = srow_st >> 4, m_st = srow_st & 15;
  int kt_st = g2 >> 1;
  int quad0 = (g2 & 1) << 1;                 // 0 or 2

  float lsum = 0.f;

  // prologue: load first tile into regs
  int tile = blockIdx.x;
  floatx4_t u[4];
  {
    int b = tile >> 4, ts = (tile & 15) << 6;
    const float* src = x + (size_t)((b << 10) + ts + srow_st) * H + (g2 << 4);
    u[0] = *(const floatx4_t*)(src);
    u[1] = *(const floatx4_t*)(src + 4);
    u[2] = *(const floatx4_t*)(src + 8);
    u[3] = *(const floatx4_t*)(src + 12);
  }

  #pragma unroll 2
  for (int it = 0; it < NT; ++it) {
    int b = tile >> 4;
    int ts = (tile & 15) << 6;               // s-base of 64-row tile
    int gb = b << 10;
    __bf16* abase = &Atile[it & 1][0][0][0][0];

    // ---- write staged regs (tile `tile`) into Atile[cur] as bf16 A-frags ----
    {
      bf16x8_t f0, f1;
      f0[0] = (__bf16)u[0][0]; f0[1] = (__bf16)u[0][1]; f0[2] = (__bf16)u[0][2]; f0[3] = (__bf16)u[0][3];
      f0[4] = (__bf16)u[1][0]; f0[5] = (__bf16)u[1][1]; f0[6] = (__bf16)u[1][2]; f0[7] = (__bf16)u[1][3];
      f1[0] = (__bf16)u[2][0]; f1[1] = (__bf16)u[2][1]; f1[2] = (__bf16)u[2][2]; f1[3] = (__bf16)u[2][3];
      f1[4] = (__bf16)u[3][0]; f1[5] = (__bf16)u[3][1]; f1[6] = (__bf16)u[3][2]; f1[7] = (__bf16)u[3][3];
      __bf16* wp = abase + (size_t)(((rowg_st * 4 + kt_st) * 64) + quad0 * 16 + m_st) * 8;
      *(bf16x8_t*)(wp) = f0;
      *(bf16x8_t*)(wp + 16 * 8) = f1;        // next quad row, +16 lanes
    }
    __syncthreads();                         // single barrier per tile (dbuf-safe)

    // ---- epilogue-source loads (exact fp32, L1/L2 hits) — issued FIRST so
    // their consumption doesn't wait on the HBM prefetch (in-order vmcnt) ----
    float yv[4][5];
    #pragma unroll
    for (int rg = 0; rg < 4; rg++) {
      int sr = ts + (rg << 4) + (quad << 2);
      const float* yp = x + (size_t)(gb + sr) * H + col;
      #pragma unroll
      for (int i2 = 0; i2 < 4; i2++) yv[rg][i2] = yp[(size_t)i2 * H];
      size_t r4 = (size_t)(gb + sr) + 4;     // row sr+4: x1 of i2=3
      if (r4 > (size_t)(NROWS_TOTAL - 1)) r4 = (size_t)(NROWS_TOTAL - 1);
      yv[rg][4] = x[r4 * H + col];
    }

    // ---- prefetch next tile into regs; lands during MFMA+epilogue ----
    {
      int ntile = tile + GRID;
      if (ntile >= 4096) ntile = blockIdx.x; // last iter: harmless dummy
      int nb = ntile >> 4, nts = (ntile & 15) << 6;
      const float* src = x + (size_t)((nb << 10) + nts + srow_st) * H + (g2 << 4);
      u[0] = *(const floatx4_t*)(src);
      u[1] = *(const floatx4_t*)(src + 4);
      u[2] = *(const floatx4_t*)(src + 8);
      u[3] = *(const floatx4_t*)(src + 12);
    }

    // ---- MFMA: this wave computes P[all 64 rows][its 16 cols] ----
    floatx4_t acc[4];                        // [rowg]
    #pragma unroll
    for (int rg = 0; rg < 4; rg++) acc[rg] = (floatx4_t){0.f, 0.f, 0.f, 0.f};
    #pragma unroll
    for (int kt = 0; kt < 4; kt++) {
      bf16x8_t af[4];
      #pragma unroll
      for (int rg = 0; rg < 4; rg++)
        af[rg] = *(const bf16x8_t*)(abase + (size_t)(((rg * 4 + kt) * 64) + lane) * 8);
      #pragma unroll
      for (int rg = 0; rg < 4; rg++)
        acc[rg] = __builtin_amdgcn_mfma_f32_16x16x32_bf16(af[rg], breg[kt], acc[rg], 0, 0, 0);
    }

    // ---- residual consume: row = rg*16 + quad*4 + i2, col = wave*16 + m;
    // x1[s] == y[s+1] -> yv[rg][i2+1] ----
    #pragma unroll
    for (int rg = 0; rg < 4; rg++) {
      int sr = ts + (rg << 4) + (quad << 2);
      #pragma unroll
      for (int i2 = 0; i2 < 4; i2++) {
        if (sr + i2 <= SEQ - 2) {
          float rr = (yv[rg][i2] - yv[rg][i2 + 1]) + acc[rg][i2];
          lsum += rr * rr;
        }
      }
    }
    tile += GRID;
  }

  #pragma unroll
  for (int off = 32; off > 0; off >>= 1) lsum += __shfl_down(lsum, off);
  __shared__ float red[8];
  if (lane == 0) red[wave] = lsum;
  __syncthreads();
  if (tid == 0) {
    float s = red[0] + red[1] + red[2] + red[3] + red[4] + red[5] + red[6] + red[7];
    atomicAdd(accum, s);
  }
}

__global__ void finalize_kernel(const float* __restrict__ accum, float* __restrict__ out) {
  out[0] = accum[0] * (1.0f / STEP_ELEMS) + 0.001f * accum[1] * (1.0f / 16384.0f);
}

extern "C" void kernel_launch(void* const* d_in, const int* in_sizes, int n_in,
                              void* d_out, int out_size, void* d_ws, size_t ws_size,
                              hipStream_t stream) {
  const float* x = (const float*)d_in[0];
  const float* C = (const float*)d_in[1];
  __bf16* Dpack = (__bf16*)d_ws;
  float* accum = (float*)((char*)d_ws + 32768);
  float* T = (float*)((char*)d_ws + 65536);
  float* out = (float*)d_out;

  prep_p1<<<64, 256, 0, stream>>>(C, T, accum);
  prep_p2<<<64, 256, 0, stream>>>(C, T, Dpack);
  sindy_main<<<GRID, 512, 0, stream>>>(x, Dpack, accum);
  finalize_kernel<<<1, 1, 0, stream>>>(accum, out);
}

// Round 6
// 215.462 us; speedup vs baseline: 1.0048x; 1.0048x over previous
//
#include <hip/hip_runtime.h>
#include <hip/hip_bf16.h>

typedef __bf16 bf16x8_t __attribute__((ext_vector_type(8)));
typedef float floatx4_t __attribute__((ext_vector_type(4)));

#define H 128
#define BATCH 256
#define SEQ 1024
#define NROWS_TOTAL (BATCH * SEQ)            // 262144 rows of x
#define STEP_ELEMS 33521664.0f               // 256*1023*128
#define GRID 1024

// ws layout: [0, 32768)      : Dpack, bf16, MFMA-B-fragment order [kt][n][lane][j]
//            [32768, 32776)  : accum[0]=step_sum, accum[1]=l2_sum
//            [65536, 131072) : T = A*A, fp32 row-major
//
// Algebra: f(y)=y@C.T is linear, so RK4 collapses to y1 = y·(I + D),
// D = A + A^2/2 + A^3/6 + A^4/24, A = C^T (truncated expm). Main pass is one
// streaming GEMM P = y·D (bf16 MFMA correction; residual (y-x1) exact fp32),
// reading x once: 134 MB -> HBM floor ~20 us.
// v6 = v4 (best, 212.4) + two WORK cuts, same 2-barrier structure:
//  (1) fp32 x-tile also staged to LDS Y[65][132] (incl. boundary row 64);
//      epilogue reads y/x1 from LDS -> zero epilogue VMEM, bit-identical math.
//  (2) 2x4 wave split (32 rows x 32 cols per wave): A-frag LDS reads halved,
//      B-regs 32 VGPR/lane. v5's reg-prefetch pipeline dropped (regressed).

// ---- prep stage 1: T = A*A (A = C^T), plus l2 term and accumulator init ----
__global__ __launch_bounds__(256) void prep_p1(const float* __restrict__ C,
                                               float* __restrict__ T,
                                               float* __restrict__ accum) {
  int e = blockIdx.x * 256 + threadIdx.x;    // 64 WGs * 256 = 16384 elements
  int i = e >> 7, j = e & 127;
  const float* Ci = C + i;                   // C[k][i], stride H — wave-broadcast
  const float* Cj = C + j * H;               // own row, stride 1
  float s = 0.f;
  #pragma unroll 8
  for (int k = 0; k < H; k++) s += Ci[k * H] * Cj[k];
  T[e] = s;

  if (blockIdx.x == 0) {
    float l2 = 0.f;
    for (int q = threadIdx.x; q < H * H; q += 256) {
      float c = C[q], c2 = c * c;
      l2 += c2 * c2;                         // sum C^4
    }
    #pragma unroll
    for (int off = 32; off > 0; off >>= 1) l2 += __shfl_down(l2, off);
    __shared__ float red[4];
    if ((threadIdx.x & 63) == 0) red[threadIdx.x >> 6] = l2;
    __syncthreads();
    if (threadIdx.x == 0) {
      accum[0] = 0.f;
      accum[1] = red[0] + red[1] + red[2] + red[3];
    }
  }
}

// ---- prep stage 2: D = A + T/2 + (T*A)/6 + (T*T)/24, packed to MFMA B-frag layout ----
__global__ __launch_bounds__(256) void prep_p2(const float* __restrict__ C,
                                               const float* __restrict__ T,
                                               __bf16* __restrict__ Dpack) {
  int e = blockIdx.x * 256 + threadIdx.x;
  int i = e >> 7, j = e & 127;
  const float* Ti = T + i * H;               // wave-broadcast row
  const float* Cj = C + j * H;               // own row
  const float* Tj = T + j;                   // column — L2-resident
  float s3 = 0.f, s4 = 0.f;
  #pragma unroll 8
  for (int k = 0; k < H; k++) {
    float t = Ti[k];
    s3 += t * Cj[k];
    s4 += t * Tj[k * H];
  }
  float d = C[j * H + i] + 0.5f * Ti[j] + s3 * (1.f / 6.f) + s4 * (1.f / 24.f);
  // pack: frag(kt,n), lane lanep, elem je holds D[kt*32 + (lanep>>4)*8 + je][n*16 + (lanep&15)]
  int kt = i >> 5, lq = (i >> 3) & 3, je = i & 7;
  int n = j >> 4, mm = j & 15;
  int lanep = lq * 16 + mm;
  Dpack[(size_t)(((kt * 8 + n) * 64 + lanep) * 8 + je)] = (__bf16)d;
}

// ---- main streaming pass: P = y*D via MFMA, residual + square + reduce ----
// 512 threads = 8 waves; wave = (wrow, wcol) owns rows [32*wrow,+32) x cols [32*wcol,+32).
__global__ __launch_bounds__(512, 4) void sindy_main(const float* __restrict__ x,
                                                     const __bf16* __restrict__ Dpack,
                                                     float* __restrict__ accum) {
  // bf16 MFMA-A fragments: [rowg][kt][lane][j], 16 KB, linear frag addressing
  __shared__ __align__(16) __bf16 Atile[4][4][64][8];
  // exact fp32 x-tile (rows 0..64 incl. boundary), pad 132 -> <=2-way conflicts
  __shared__ __align__(16) float Y[65][132];

  int tid = threadIdx.x;
  int lane = tid & 63;
  int wave = tid >> 6;
  int m = lane & 15, quad = lane >> 4;
  int wrow = wave >> 2;                      // 0..1
  int wcol = wave & 3;                       // 0..3

  // B fragments: n = wcol*2 + n2  -> 8 frags = 32 VGPRs
  bf16x8_t breg[2][4];
  const bf16x8_t* Dp = (const bf16x8_t*)Dpack;
  #pragma unroll
  for (int n2 = 0; n2 < 2; n2++)
    #pragma unroll
    for (int kt = 0; kt < 4; kt++)
      breg[n2][kt] = Dp[(kt * 8 + wcol * 2 + n2) * 64 + lane];

  // staging coords: thread loads row (tid>>3), 16-col group (tid&7)
  int srow_st = tid >> 3;                    // 0..63
  int g2 = tid & 7;
  int rowg_st = srow_st >> 4, m_st = srow_st & 15;
  int kt_st = g2 >> 1;
  int quad0 = (g2 & 1) << 1;                 // 0 or 2

  float lsum = 0.f;

  for (int tile = blockIdx.x; tile < 4096; tile += GRID) {
    int b = tile >> 4;
    int ts = (tile & 15) << 6;               // s-base of 64-row tile
    int gb = b << 10;

    // ---- stage: 64x128 fp32 -> Y (exact) and Atile (bf16 A-frags) ----
    {
      const float* src = x + (size_t)(gb + ts + srow_st) * H + (g2 << 4);
      floatx4_t u0 = *(const floatx4_t*)(src);
      floatx4_t u1 = *(const floatx4_t*)(src + 4);
      floatx4_t u2 = *(const floatx4_t*)(src + 8);
      floatx4_t u3 = *(const floatx4_t*)(src + 12);
      float* yw = &Y[srow_st][g2 << 4];
      *(floatx4_t*)(yw) = u0;
      *(floatx4_t*)(yw + 4) = u1;
      *(floatx4_t*)(yw + 8) = u2;
      *(floatx4_t*)(yw + 12) = u3;
      bf16x8_t f0, f1;
      f0[0] = (__bf16)u0[0]; f0[1] = (__bf16)u0[1]; f0[2] = (__bf16)u0[2]; f0[3] = (__bf16)u0[3];
      f0[4] = (__bf16)u1[0]; f0[5] = (__bf16)u1[1]; f0[6] = (__bf16)u1[2]; f0[7] = (__bf16)u1[3];
      f1[0] = (__bf16)u2[0]; f1[1] = (__bf16)u2[1]; f1[2] = (__bf16)u2[2]; f1[3] = (__bf16)u2[3];
      f1[4] = (__bf16)u3[0]; f1[5] = (__bf16)u3[1]; f1[6] = (__bf16)u3[2]; f1[7] = (__bf16)u3[3];
      *(bf16x8_t*)&Atile[rowg_st][kt_st][(quad0 + 0) * 16 + m_st][0] = f0;
      *(bf16x8_t*)&Atile[rowg_st][kt_st][(quad0 + 1) * 16 + m_st][0] = f1;
      // boundary row 64 (x1 of local row 63): 8 threads, clamped in-bounds
      if (tid < 8) {
        size_t grow = (size_t)(gb + ts) + 64;
        if (grow > (size_t)(NROWS_TOTAL - 1)) grow = (size_t)(NROWS_TOTAL - 1);
        const float* s2 = x + grow * H + (tid << 4);
        float* yb = &Y[64][tid << 4];
        *(floatx4_t*)(yb)      = *(const floatx4_t*)(s2);
        *(floatx4_t*)(yb + 4)  = *(const floatx4_t*)(s2 + 4);
        *(floatx4_t*)(yb + 8)  = *(const floatx4_t*)(s2 + 8);
        *(floatx4_t*)(yb + 12) = *(const floatx4_t*)(s2 + 12);
      }
    }
    __syncthreads();

    // ---- MFMA: acc[rg2][n2] over 4 k-tiles ----
    floatx4_t acc[2][2];
    #pragma unroll
    for (int rg2 = 0; rg2 < 2; rg2++)
      #pragma unroll
      for (int n2 = 0; n2 < 2; n2++) acc[rg2][n2] = (floatx4_t){0.f, 0.f, 0.f, 0.f};
    #pragma unroll
    for (int kt = 0; kt < 4; kt++) {
      bf16x8_t af[2];
      #pragma unroll
      for (int rg2 = 0; rg2 < 2; rg2++)
        af[rg2] = *(const bf16x8_t*)&Atile[wrow * 2 + rg2][kt][lane][0];
      #pragma unroll
      for (int rg2 = 0; rg2 < 2; rg2++)
        #pragma unroll
        for (int n2 = 0; n2 < 2; n2++)
          acc[rg2][n2] = __builtin_amdgcn_mfma_f32_16x16x32_bf16(af[rg2], breg[n2][kt], acc[rg2][n2], 0, 0, 0);
    }

    // ---- residual from LDS (exact fp32): row = wrow*32+rg2*16+quad*4+i2,
    // col = wcol*32+n2*16+m; x1[s] = Y[s_local+1] ----
    #pragma unroll
    for (int rg2 = 0; rg2 < 2; rg2++) {
      int sl0 = (wrow << 5) + (rg2 << 4) + (quad << 2);  // local row base
      int sg0 = ts + sl0;                                // global seq pos
      #pragma unroll
      for (int n2 = 0; n2 < 2; n2++) {
        int c = (wcol << 5) + (n2 << 4) + m;
        float yv[5];
        #pragma unroll
        for (int t = 0; t < 5; t++) yv[t] = Y[sl0 + t][c];
        #pragma unroll
        for (int i2 = 0; i2 < 4; i2++) {
          if (sg0 + i2 <= SEQ - 2) {
            float rr = (yv[i2] - yv[i2 + 1]) + acc[rg2][n2][i2];
            lsum += rr * rr;
          }
        }
      }
    }
    __syncthreads();                         // protect Atile/Y before next stage
  }

  #pragma unroll
  for (int off = 32; off > 0; off >>= 1) lsum += __shfl_down(lsum, off);
  __shared__ float red[8];
  if (lane == 0) red[wave] = lsum;
  __syncthreads();
  if (tid == 0) {
    float s = red[0] + red[1] + red[2] + red[3] + red[4] + red[5] + red[6] + red[7];
    atomicAdd(accum, s);
  }
}

__global__ void finalize_kernel(const float* __restrict__ accum, float* __restrict__ out) {
  out[0] = accum[0] * (1.0f / STEP_ELEMS) + 0.001f * accum[1] * (1.0f / 16384.0f);
}

extern "C" void kernel_launch(void* const* d_in, const int* in_sizes, int n_in,
                              void* d_out, int out_size, void* d_ws, size_t ws_size,
                              hipStream_t stream) {
  const float* x = (const float*)d_in[0];
  const float* C = (const float*)d_in[1];
  __bf16* Dpack = (__bf16*)d_ws;
  float* accum = (float*)((char*)d_ws + 32768);
  float* T = (float*)((char*)d_ws + 65536);
  float* out = (float*)d_out;

  prep_p1<<<64, 256, 0, stream>>>(C, T, accum);
  prep_p2<<<64, 256, 0, stream>>>(C, T, Dpack);
  sindy_main<<<GRID, 512, 0, stream>>>(x, Dpack, accum);
  finalize_kernel<<<1, 1, 0, stream>>>(accum, out);
}